// Round 1
// baseline (13047.681 us; speedup 1.0000x reference)
//
#include <hip/hip_runtime.h>

constexpr int kB = 256;
constexpr int kS = 512;
constexpr int kU = 256;
constexpr int kZ = 256;

__device__ __forceinline__ float sigm(float x) {
    return 1.0f / (1.0f + __expf(-x));
}
__device__ __forceinline__ float tanh_fast(float x) {
    float ax = fabsf(x);
    float e = __expf(-2.0f * ax);
    float t = (1.0f - e) / (1.0f + e);
    return x < 0.0f ? -t : t;
}

// Extract component kk (kk must be a compile-time constant after unrolling).
#define F4C(v, kk) ((kk) == 0 ? (v).x : (kk) == 1 ? (v).y : (kk) == 2 ? (v).z : (v).w)

// ---------------------------------------------------------------------------
// Phase 1: sequential recurrence. 64 blocks x 256 threads, 4 batch rows/block.
// Writes g = o * h1 into d_out (same layout as final output, reused as scratch).
// ---------------------------------------------------------------------------
__global__ __launch_bounds__(256) void rnn_phase1(
    const int* __restrict__ z,
    const float* __restrict__ hW, const float* __restrict__ hU, const float* __restrict__ hb,
    const float* __restrict__ fW, const float* __restrict__ fb,
    const float* __restrict__ iW, const float* __restrict__ ib,
    const float* __restrict__ cW, const float* __restrict__ cb,
    const float* __restrict__ oW, const float* __restrict__ ob,
    const float* __restrict__ h0,
    float* __restrict__ out)
{
    __shared__ __align__(16) float h1s[2][4][kU];  // double-buffered carry state
    __shared__ __align__(16) float hs[4][kU];      // current h

    const int j  = threadIdx.x;      // output column owned by this thread
    const int b0 = blockIdx.x * 4;   // first batch row of this block

    const float h0j = h0[j];
    #pragma unroll
    for (int r = 0; r < 4; ++r) h1s[0][r][j] = h0j;

    const float hbj = hb[j];
    const float fbj = fb[j], ibj = ib[j], cbj = cb[j], obj = ob[j];
    __syncthreads();

    for (int t = 0; t < kS; ++t) {
        const int p = t & 1;

        // embedding + bias (zshifted: t==0 -> 0 else z[:,t-1]+1)
        float a[4];
        #pragma unroll
        for (int r = 0; r < 4; ++r) {
            const int zt = (t == 0) ? 0 : (z[(b0 + r) * kS + t - 1] + 1);
            a[r] = hW[zt * kU + j] + hbj;
        }

        // a += h1_prev @ h_U   (column j, 4 rows)
        #pragma unroll 4
        for (int k = 0; k < kU; k += 4) {
            float4 x[4];
            #pragma unroll
            for (int r = 0; r < 4; ++r) x[r] = *(const float4*)&h1s[p][r][k];
            #pragma unroll
            for (int kk = 0; kk < 4; ++kk) {
                const float w = hU[(k + kk) * kU + j];
                #pragma unroll
                for (int r = 0; r < 4; ++r) a[r] += F4C(x[r], kk) * w;
            }
        }

        #pragma unroll
        for (int r = 0; r < 4; ++r) hs[r][j] = tanh_fast(a[r]);
        __syncthreads();

        // gates: f,i,c,o = act(h @ W_m + b_m)
        float af[4], ai[4], ac[4], ao[4];
        #pragma unroll
        for (int r = 0; r < 4; ++r) { af[r] = fbj; ai[r] = ibj; ac[r] = cbj; ao[r] = obj; }

        #pragma unroll 2
        for (int k = 0; k < kU; k += 4) {
            float4 x[4];
            #pragma unroll
            for (int r = 0; r < 4; ++r) x[r] = *(const float4*)&hs[r][k];
            #pragma unroll
            for (int kk = 0; kk < 4; ++kk) {
                const float wf = fW[(k + kk) * kU + j];
                const float wi = iW[(k + kk) * kU + j];
                const float wc = cW[(k + kk) * kU + j];
                const float wo = oW[(k + kk) * kU + j];
                #pragma unroll
                for (int r = 0; r < 4; ++r) {
                    const float e = F4C(x[r], kk);
                    af[r] += e * wf; ai[r] += e * wi;
                    ac[r] += e * wc; ao[r] += e * wo;
                }
            }
        }

        // h1_new = h1_prev*f + c*i ; stash g = o*h1_new in d_out
        #pragma unroll
        for (int r = 0; r < 4; ++r) {
            const float fg  = sigm(af[r]);
            const float ig  = sigm(ai[r]);
            const float cg  = tanh_fast(ac[r]);
            const float og  = sigm(ao[r]);
            const float h1n = h1s[p][r][j] * fg + cg * ig;
            out[((size_t)(b0 + r) * kS + t) * kU + j] = og * h1n;
            h1s[p ^ 1][r][j] = h1n;
        }
        __syncthreads();
    }
}

// ---------------------------------------------------------------------------
// Phase 2: fully parallel output head. 4096 blocks x 256 threads, 32 rows/block.
// Reads g from d_out, computes t = tanh(g@t_W+t_b), y = softmax(t@y_W+y_b),
// overwrites d_out in place (block owns its 32 rows exclusively).
// ---------------------------------------------------------------------------
__global__ __launch_bounds__(256) void rnn_phase2(
    const float* __restrict__ tW, const float* __restrict__ tb,
    const float* __restrict__ yW, const float* __restrict__ yb,
    float* __restrict__ out)
{
    __shared__ __align__(16) float gl[32][kU];
    __shared__ __align__(16) float tl[32][kU];

    const int c = threadIdx.x;
    const size_t rowbase = (size_t)blockIdx.x * 32;

    for (int idx = c; idx < 32 * kU; idx += 256) {
        const int r = idx >> 8, col = idx & 255;
        gl[r][col] = out[(rowbase + r) * kU + col];
    }
    __syncthreads();

    float acc[32];
    {
        const float tbc = tb[c];
        #pragma unroll
        for (int r = 0; r < 32; ++r) acc[r] = tbc;
    }
    #pragma unroll 2
    for (int k = 0; k < kU; k += 4) {
        const float w0 = tW[(k + 0) * kU + c];
        const float w1 = tW[(k + 1) * kU + c];
        const float w2 = tW[(k + 2) * kU + c];
        const float w3 = tW[(k + 3) * kU + c];
        #pragma unroll
        for (int r = 0; r < 32; ++r) {
            const float4 g4 = *(const float4*)&gl[r][k];
            acc[r] += g4.x * w0 + g4.y * w1 + g4.z * w2 + g4.w * w3;
        }
    }
    #pragma unroll
    for (int r = 0; r < 32; ++r) tl[r][c] = tanh_fast(acc[r]);
    __syncthreads();

    {
        const float ybc = yb[c];
        #pragma unroll
        for (int r = 0; r < 32; ++r) acc[r] = ybc;
    }
    #pragma unroll 2
    for (int k = 0; k < kU; k += 4) {
        const float w0 = yW[(k + 0) * kU + c];
        const float w1 = yW[(k + 1) * kU + c];
        const float w2 = yW[(k + 2) * kU + c];
        const float w3 = yW[(k + 3) * kU + c];
        #pragma unroll
        for (int r = 0; r < 32; ++r) {
            const float4 t4 = *(const float4*)&tl[r][k];
            acc[r] += t4.x * w0 + t4.y * w1 + t4.z * w2 + t4.w * w3;
        }
    }

    // logits -> LDS (reuse gl), then per-wave softmax over 8 rows each
    #pragma unroll
    for (int r = 0; r < 32; ++r) gl[r][c] = acc[r];
    __syncthreads();

    const int wv = c >> 6, lane = c & 63;
    for (int q = 0; q < 8; ++q) {
        const int r = wv * 8 + q;
        const float4 v = *(const float4*)&gl[r][lane * 4];
        float m = fmaxf(fmaxf(v.x, v.y), fmaxf(v.z, v.w));
        #pragma unroll
        for (int off = 32; off > 0; off >>= 1) m = fmaxf(m, __shfl_xor(m, off, 64));
        const float e0 = __expf(v.x - m), e1 = __expf(v.y - m);
        const float e2 = __expf(v.z - m), e3 = __expf(v.w - m);
        float s = e0 + e1 + e2 + e3;
        #pragma unroll
        for (int off = 32; off > 0; off >>= 1) s += __shfl_xor(s, off, 64);
        const float inv = 1.0f / s;
        float4 o4; o4.x = e0 * inv; o4.y = e1 * inv; o4.z = e2 * inv; o4.w = e3 * inv;
        *(float4*)&out[(rowbase + r) * kU + lane * 4] = o4;
    }
}

extern "C" void kernel_launch(void* const* d_in, const int* in_sizes, int n_in,
                              void* d_out, int out_size, void* d_ws, size_t ws_size,
                              hipStream_t stream) {
    const int*   z  = (const int*)d_in[0];
    const float* hW = (const float*)d_in[1];
    const float* hU = (const float*)d_in[2];
    const float* hb = (const float*)d_in[3];
    const float* fW = (const float*)d_in[4];
    const float* fb = (const float*)d_in[5];
    const float* iW = (const float*)d_in[6];
    const float* ib = (const float*)d_in[7];
    const float* cW = (const float*)d_in[8];
    const float* cb = (const float*)d_in[9];
    const float* oW = (const float*)d_in[10];
    const float* ob = (const float*)d_in[11];
    const float* tW = (const float*)d_in[12];
    const float* tb = (const float*)d_in[13];
    const float* yW = (const float*)d_in[14];
    const float* yb = (const float*)d_in[15];
    const float* h0 = (const float*)d_in[16];
    float* out = (float*)d_out;

    rnn_phase1<<<dim3(kB / 4), dim3(256), 0, stream>>>(
        z, hW, hU, hb, fW, fb, iW, ib, cW, cb, oW, ob, h0, out);
    rnn_phase2<<<dim3((kB * kS) / 32), dim3(256), 0, stream>>>(
        tW, tb, yW, yb, out);
}

// Round 2
// 4341.184 us; speedup vs baseline: 3.0056x; 3.0056x over previous
//
#include <hip/hip_runtime.h>

constexpr int kB = 256;
constexpr int kS = 512;
constexpr int kU = 256;

typedef _Float16 half2v __attribute__((ext_vector_type(2)));

__device__ __forceinline__ float sigm(float x) {
    return 1.0f / (1.0f + __expf(-x));
}
__device__ __forceinline__ float tanh_fast(float x) {
    float ax = fabsf(x);
    float e = __expf(-2.0f * ax);
    float t = (1.0f - e) / (1.0f + e);
    return x < 0.0f ? -t : t;
}
__device__ __forceinline__ float dot2(unsigned w, unsigned h, float acc) {
    return __builtin_amdgcn_fdot2(__builtin_bit_cast(half2v, w),
                                  __builtin_bit_cast(half2v, h), acc, false);
}
__device__ __forceinline__ unsigned packh2(float lo, float hi) {
    half2v h; h.x = (_Float16)lo; h.y = (_Float16)hi;
    return __builtin_bit_cast(unsigned, h);
}

#define U4C(v, kk) ((kk) == 0 ? (v).x : (kk) == 1 ? (v).y : (kk) == 2 ? (v).z : (v).w)

// ws layout (uint32 units): [hU | fW | iW | cW | oW | tW | yW], each 32768 u32.
// pk[mat][kp*256 + j] = f16pair( W[2kp][j], W[2kp+1][j] )
constexpr int kMatU32 = 32768;

// ---------------------------------------------------------------------------
// Phase 0: convert the 7 matmul weight matrices to packed fp16 pairs.
// ---------------------------------------------------------------------------
__global__ __launch_bounds__(256) void convert_weights(
    const float* __restrict__ hU, const float* __restrict__ fW,
    const float* __restrict__ iW, const float* __restrict__ cW,
    const float* __restrict__ oW, const float* __restrict__ tW,
    const float* __restrict__ yW, unsigned* __restrict__ wpk)
{
    const int idx = blockIdx.x * 256 + threadIdx.x;   // 7*32768 total
    const int mat = idx >> 15;
    const int r   = idx & (kMatU32 - 1);
    const int kp  = r >> 8;
    const int j   = r & 255;
    const float* W = mat == 0 ? hU : mat == 1 ? fW : mat == 2 ? iW :
                     mat == 3 ? cW : mat == 4 ? oW : mat == 5 ? tW : yW;
    const float w0 = W[(2 * kp) * kU + j];
    const float w1 = W[(2 * kp + 1) * kU + j];
    wpk[idx] = packh2(w0, w1);
}

// ---------------------------------------------------------------------------
// Phase 1: sequential recurrence.
// 128 blocks x 1024 threads (16 waves). 2 batch rows per block.
// Thread (j = tid&255, kq = tid>>8): k-chunk kq of the 256-long reduction.
// h1 master copy: fp32 register in threads kq<2 (row r = kq).
// Matvec inputs packed fp16 in LDS; weights packed fp16 from ws (L2-resident).
// Writes g = o*h1 into d_out (reused as scratch, same layout as final output).
// ---------------------------------------------------------------------------
__global__ __launch_bounds__(1024) void rnn_phase1(
    const int* __restrict__ z,
    const float* __restrict__ hW, const float* __restrict__ hb,
    const float* __restrict__ fb, const float* __restrict__ ib,
    const float* __restrict__ cb, const float* __restrict__ ob,
    const float* __restrict__ h0,
    const unsigned* __restrict__ wpk,
    float* __restrict__ out)
{
    __shared__ unsigned h1pk[2][2][kU / 2];        // double-buffered packed h1
    __shared__ unsigned hspk[2][kU / 2];           // packed h
    __shared__ float    partA[4][2][kU];           // hU partials [kq][r][j]
    __shared__ float    partG[4][4][2][kU];        // gate partials [kq][mat][r][j]
    __shared__ float    gact[4][2][kU];            // activated gates [mat][r][j]

    const int tid = threadIdx.x;
    const int j   = tid & 255;
    const int kq  = tid >> 8;                      // 0..3
    const int b0  = blockIdx.x * 2;
    const int kbase = kq * 32;                     // k-pair base for this chunk

    const unsigned* __restrict__ hUpk = wpk;
    const unsigned* __restrict__ fpk  = wpk + 1 * kMatU32;
    const unsigned* __restrict__ ipk  = wpk + 2 * kMatU32;
    const unsigned* __restrict__ cpk  = wpk + 3 * kMatU32;
    const unsigned* __restrict__ opk  = wpk + 4 * kMatU32;

    // per-role constants
    const float hbj  = hb[j];
    const float bsel = (kq == 0 ? fb : kq == 1 ? ib : kq == 2 ? cb : ob)[j];

    // init h1 (fp32 master in register for kq<2) + packed copy in LDS
    float h1reg = 0.0f;
    if (kq < 2) {
        h1reg = h0[j];
        const float hhi = __shfl_down(h1reg, 1, 64);
        if ((j & 1) == 0) h1pk[0][kq][j >> 1] = packh2(h1reg, hhi);
    }
    __syncthreads();

    for (int t = 0; t < kS; ++t) {
        const int p = t & 1;

        // embedding preload (reduce threads only; latency hidden under partials)
        float emb = 0.0f;
        if (kq < 2) {
            const int zt = (t == 0) ? 0 : (z[(b0 + kq) * kS + t - 1] + 1);
            emb = hW[zt * kU + j];
        }

        // ---- hU partials over this k-chunk ----
        float a0 = 0.0f, a1 = 0.0f;
        #pragma unroll 4
        for (int i4 = 0; i4 < 8; ++i4) {
            const int kk = kbase + i4 * 4;
            const uint4 hp0 = *(const uint4*)&h1pk[p][0][kk];
            const uint4 hp1 = *(const uint4*)&h1pk[p][1][kk];
            #pragma unroll
            for (int q = 0; q < 4; ++q) {
                const unsigned w = hUpk[(kk + q) * kU + j];
                a0 = dot2(w, U4C(hp0, q), a0);
                a1 = dot2(w, U4C(hp1, q), a1);
            }
        }
        partA[kq][0][j] = a0;
        partA[kq][1][j] = a1;
        __syncthreads();

        // ---- reduce + tanh + pack h ----
        if (kq < 2) {
            const float a = emb + hbj + partA[0][kq][j] + partA[1][kq][j]
                          + partA[2][kq][j] + partA[3][kq][j];
            const float h  = tanh_fast(a);
            const float hh = __shfl_down(h, 1, 64);
            if ((j & 1) == 0) hspk[kq][j >> 1] = packh2(h, hh);
        }
        __syncthreads();

        // ---- gate partials (f,i,c,o) over this k-chunk ----
        float af0 = 0.f, af1 = 0.f, ai0 = 0.f, ai1 = 0.f;
        float ac0 = 0.f, ac1 = 0.f, ao0 = 0.f, ao1 = 0.f;
        #pragma unroll 2
        for (int i4 = 0; i4 < 8; ++i4) {
            const int kk = kbase + i4 * 4;
            const uint4 hp0 = *(const uint4*)&hspk[0][kk];
            const uint4 hp1 = *(const uint4*)&hspk[1][kk];
            #pragma unroll
            for (int q = 0; q < 4; ++q) {
                const int off = (kk + q) * kU + j;
                const unsigned wf = fpk[off];
                const unsigned wi = ipk[off];
                const unsigned wc = cpk[off];
                const unsigned wo = opk[off];
                const unsigned g0 = U4C(hp0, q);
                const unsigned g1 = U4C(hp1, q);
                af0 = dot2(wf, g0, af0);  af1 = dot2(wf, g1, af1);
                ai0 = dot2(wi, g0, ai0);  ai1 = dot2(wi, g1, ai1);
                ac0 = dot2(wc, g0, ac0);  ac1 = dot2(wc, g1, ac1);
                ao0 = dot2(wo, g0, ao0);  ao1 = dot2(wo, g1, ao1);
            }
        }
        partG[kq][0][0][j] = af0;  partG[kq][0][1][j] = af1;
        partG[kq][1][0][j] = ai0;  partG[kq][1][1][j] = ai1;
        partG[kq][2][0][j] = ac0;  partG[kq][2][1][j] = ac1;
        partG[kq][3][0][j] = ao0;  partG[kq][3][1][j] = ao1;
        __syncthreads();

        // ---- gate reduce + activation: thread handles mat = kq, both rows ----
        {
            const float s0 = bsel + partG[0][kq][0][j] + partG[1][kq][0][j]
                           + partG[2][kq][0][j] + partG[3][kq][0][j];
            const float s1 = bsel + partG[0][kq][1][j] + partG[1][kq][1][j]
                           + partG[2][kq][1][j] + partG[3][kq][1][j];
            if (kq == 2) { gact[kq][0][j] = tanh_fast(s0); gact[kq][1][j] = tanh_fast(s1); }
            else         { gact[kq][0][j] = sigm(s0);      gact[kq][1][j] = sigm(s1); }
        }
        __syncthreads();

        // ---- state update + g output ----
        if (kq < 2) {
            const float f = gact[0][kq][j];
            const float i = gact[1][kq][j];
            const float c = gact[2][kq][j];
            const float o = gact[3][kq][j];
            h1reg = h1reg * f + c * i;
            out[((size_t)(b0 + kq) * kS + t) * kU + j] = o * h1reg;
            const float hh = __shfl_down(h1reg, 1, 64);
            if ((j & 1) == 0) h1pk[p ^ 1][kq][j >> 1] = packh2(h1reg, hh);
        }
        __syncthreads();
    }
}

// ---------------------------------------------------------------------------
// Phase 2: output head. 4096 blocks x 256 threads, 32 rows/block.
// dot2 fp16 matvecs; softmax fp32. In-place on d_out.
// ---------------------------------------------------------------------------
__global__ __launch_bounds__(256) void rnn_phase2(
    const float* __restrict__ tb, const float* __restrict__ yb,
    const unsigned* __restrict__ wpk,
    float* __restrict__ out)
{
    __shared__ float    lg[32][kU];        // g staging, then logits
    __shared__ unsigned xpk[32][kU / 2];   // packed g, then packed t

    const unsigned* __restrict__ tWpk = wpk + 5 * kMatU32;
    const unsigned* __restrict__ yWpk = wpk + 6 * kMatU32;

    const int c = threadIdx.x;
    const size_t rowbase = (size_t)blockIdx.x * 32;

    // stage g rows (coalesced float4)
    {
        const float4* src = (const float4*)&out[rowbase * kU];
        float4* dst = (float4*)&lg[0][0];
        #pragma unroll
        for (int i = 0; i < 8; ++i) dst[i * 256 + c] = src[i * 256 + c];
    }
    __syncthreads();

    // pack g -> fp16 pairs
    #pragma unroll
    for (int i = 0; i < 16; ++i) {
        const int flat = i * 256 + c;
        const int r = flat >> 7, kp = flat & 127;
        xpk[r][kp] = packh2(lg[r][2 * kp], lg[r][2 * kp + 1]);
    }
    __syncthreads();

    float acc[32];

    // ---- t = tanh(g @ tW + tb) ----
    {
        const float tbc = tb[c];
        #pragma unroll
        for (int r = 0; r < 32; ++r) acc[r] = tbc;
    }
    #pragma unroll 2
    for (int kp4 = 0; kp4 < 32; ++kp4) {
        const unsigned w0 = tWpk[(4 * kp4 + 0) * kU + c];
        const unsigned w1 = tWpk[(4 * kp4 + 1) * kU + c];
        const unsigned w2 = tWpk[(4 * kp4 + 2) * kU + c];
        const unsigned w3 = tWpk[(4 * kp4 + 3) * kU + c];
        #pragma unroll
        for (int r = 0; r < 32; ++r) {
            const uint4 g4 = *(const uint4*)&xpk[r][4 * kp4];
            acc[r] = dot2(w0, g4.x, acc[r]);
            acc[r] = dot2(w1, g4.y, acc[r]);
            acc[r] = dot2(w2, g4.z, acc[r]);
            acc[r] = dot2(w3, g4.w, acc[r]);
        }
    }
    __syncthreads();   // all xpk reads done before overwrite

    // pack t (pairs along c via shfl)
    #pragma unroll
    for (int r = 0; r < 32; ++r) {
        const float th = tanh_fast(acc[r]);
        const float hh = __shfl_down(th, 1, 64);
        if ((c & 1) == 0) xpk[r][c >> 1] = packh2(th, hh);
    }
    __syncthreads();

    // ---- logits = t @ yW + yb ----
    {
        const float ybc = yb[c];
        #pragma unroll
        for (int r = 0; r < 32; ++r) acc[r] = ybc;
    }
    #pragma unroll 2
    for (int kp4 = 0; kp4 < 32; ++kp4) {
        const unsigned w0 = yWpk[(4 * kp4 + 0) * kU + c];
        const unsigned w1 = yWpk[(4 * kp4 + 1) * kU + c];
        const unsigned w2 = yWpk[(4 * kp4 + 2) * kU + c];
        const unsigned w3 = yWpk[(4 * kp4 + 3) * kU + c];
        #pragma unroll
        for (int r = 0; r < 32; ++r) {
            const uint4 t4 = *(const uint4*)&xpk[r][4 * kp4];
            acc[r] = dot2(w0, t4.x, acc[r]);
            acc[r] = dot2(w1, t4.y, acc[r]);
            acc[r] = dot2(w2, t4.z, acc[r]);
            acc[r] = dot2(w3, t4.w, acc[r]);
        }
    }

    #pragma unroll
    for (int r = 0; r < 32; ++r) lg[r][c] = acc[r];
    __syncthreads();

    // softmax: 4 waves x 8 rows each
    const int wv = c >> 6, lane = c & 63;
    for (int q = 0; q < 8; ++q) {
        const int r = wv * 8 + q;
        const float4 v = *(const float4*)&lg[r][lane * 4];
        float m = fmaxf(fmaxf(v.x, v.y), fmaxf(v.z, v.w));
        #pragma unroll
        for (int off = 32; off > 0; off >>= 1) m = fmaxf(m, __shfl_xor(m, off, 64));
        const float e0 = __expf(v.x - m), e1 = __expf(v.y - m);
        const float e2 = __expf(v.z - m), e3 = __expf(v.w - m);
        float s = e0 + e1 + e2 + e3;
        #pragma unroll
        for (int off = 32; off > 0; off >>= 1) s += __shfl_xor(s, off, 64);
        const float inv = 1.0f / s;
        float4 o4; o4.x = e0 * inv; o4.y = e1 * inv; o4.z = e2 * inv; o4.w = e3 * inv;
        *(float4*)&out[(rowbase + r) * kU + lane * 4] = o4;
    }
}

extern "C" void kernel_launch(void* const* d_in, const int* in_sizes, int n_in,
                              void* d_out, int out_size, void* d_ws, size_t ws_size,
                              hipStream_t stream) {
    const int*   z  = (const int*)d_in[0];
    const float* hW = (const float*)d_in[1];
    const float* hU = (const float*)d_in[2];
    const float* hb = (const float*)d_in[3];
    const float* fW = (const float*)d_in[4];
    const float* fb = (const float*)d_in[5];
    const float* iW = (const float*)d_in[6];
    const float* ib = (const float*)d_in[7];
    const float* cW = (const float*)d_in[8];
    const float* cb = (const float*)d_in[9];
    const float* oW = (const float*)d_in[10];
    const float* ob = (const float*)d_in[11];
    const float* tW = (const float*)d_in[12];
    const float* tb = (const float*)d_in[13];
    const float* yW = (const float*)d_in[14];
    const float* yb = (const float*)d_in[15];
    const float* h0 = (const float*)d_in[16];
    float* out = (float*)d_out;
    unsigned* wpk = (unsigned*)d_ws;   // 7*32768 u32 = 896 KiB

    convert_weights<<<dim3(7 * kMatU32 / 256), dim3(256), 0, stream>>>(
        hU, fW, iW, cW, oW, tW, yW, wpk);
    rnn_phase1<<<dim3(kB / 2), dim3(1024), 0, stream>>>(
        z, hW, hb, fb, ib, cb, ob, h0, wpk, out);
    rnn_phase2<<<dim3((kB * kS) / 32), dim3(256), 0, stream>>>(
        tb, yb, wpk, out);
}

// Round 3
// 3490.384 us; speedup vs baseline: 3.7382x; 1.2438x over previous
//
#include <hip/hip_runtime.h>

constexpr int kB = 256;
constexpr int kS = 512;
constexpr int kU = 256;

typedef _Float16 f16x2 __attribute__((ext_vector_type(2)));
typedef _Float16 f16x8 __attribute__((ext_vector_type(8)));
typedef float    f32x4 __attribute__((ext_vector_type(4)));

__device__ __forceinline__ float sigm(float x) {
    return 1.0f / (1.0f + __expf(-x));
}
__device__ __forceinline__ float tanh_fast(float x) {
    float ax = fabsf(x);
    float e = __expf(-2.0f * ax);
    float t = (1.0f - e) / (1.0f + e);
    return x < 0.0f ? -t : t;
}
__device__ __forceinline__ float dot2(unsigned w, unsigned h, float acc) {
    return __builtin_amdgcn_fdot2(__builtin_bit_cast(f16x2, w),
                                  __builtin_bit_cast(f16x2, h), acc, false);
}
__device__ __forceinline__ unsigned packh2(float lo, float hi) {
    f16x2 h; h.x = (_Float16)lo; h.y = (_Float16)hi;
    return __builtin_bit_cast(unsigned, h);
}

// ---------------------------------------------------------------------------
// ws layout:
//   [0 .. 5*8192)  uint4  : B-fragment weights for hU,fW,iW,cW,oW (phase 1)
//                           frag idx = mat*8192 + (nt*8 + kt)*64 + lane
//                           lane l: n = nt*16 + (l&15), k0 = kt*32 + 8*(l>>4)
//                           holds fp16 W[k0..k0+7][n]
//   then (u32 idx 5*32768 ..) packed-pair tW, yW for phase 2 (round-2 layout)
// ---------------------------------------------------------------------------
constexpr int kMatU32 = 32768;   // u32 per matrix (both layouts)

__global__ __launch_bounds__(256) void convert_frag(
    const float* __restrict__ hU, const float* __restrict__ fW,
    const float* __restrict__ iW, const float* __restrict__ cW,
    const float* __restrict__ oW, uint4* __restrict__ wfrag)
{
    const int idx = blockIdx.x * 256 + threadIdx.x;   // 5*8192
    const int mat = idx >> 13;
    const int r   = idx & 8191;
    const int lane = r & 63;
    const int kt   = (r >> 6) & 7;
    const int nt   = r >> 9;
    const float* W = mat == 0 ? hU : mat == 1 ? fW : mat == 2 ? iW :
                     mat == 3 ? cW : oW;
    const int n  = nt * 16 + (lane & 15);
    const int k0 = kt * 32 + 8 * (lane >> 4);
    uint4 u;
    u.x = packh2(W[(k0 + 0) * kU + n], W[(k0 + 1) * kU + n]);
    u.y = packh2(W[(k0 + 2) * kU + n], W[(k0 + 3) * kU + n]);
    u.z = packh2(W[(k0 + 4) * kU + n], W[(k0 + 5) * kU + n]);
    u.w = packh2(W[(k0 + 6) * kU + n], W[(k0 + 7) * kU + n]);
    wfrag[idx] = u;
}

__global__ __launch_bounds__(256) void convert_pk(
    const float* __restrict__ tW, const float* __restrict__ yW,
    unsigned* __restrict__ wpk)
{
    const int idx = blockIdx.x * 256 + threadIdx.x;   // 2*32768
    const int mat = idx >> 15;
    const int r   = idx & (kMatU32 - 1);
    const int kp  = r >> 8;
    const int j   = r & 255;
    const float* W = mat == 0 ? tW : yW;
    wpk[idx] = packh2(W[(2 * kp) * kU + j], W[(2 * kp + 1) * kU + j]);
}

// ---------------------------------------------------------------------------
// Phase 1: sequential recurrence, MFMA version.
// 16 blocks x 1024 threads (16 waves). 16 batch rows per block (M=16).
// Wave w owns output-column tile n = w*16..w*16+15 for all matvecs.
// h/h1 staged in XOR-swizzled LDS tiles, read back as 16x16x32 A-fragments.
// h1 master copy fp32 in registers (D-layout). 2 barriers/step.
// Writes g = o*h1 into d_out (reused as scratch).
// ---------------------------------------------------------------------------
__global__ __launch_bounds__(1024, 1) void rnn_phase1(
    const int* __restrict__ z,
    const float* __restrict__ hW, const float* __restrict__ hb,
    const float* __restrict__ fb, const float* __restrict__ ib,
    const float* __restrict__ cb, const float* __restrict__ ob,
    const float* __restrict__ h0,
    const uint4* __restrict__ wfrag,
    float* __restrict__ out)
{
    __shared__ int zs[16 * kS];                          // 32 KB
    __shared__ __align__(16) _Float16 h1A[2][16 * kU];   // 2 x 8 KB, swizzled
    __shared__ __align__(16) _Float16 hA[16 * kU];       // 8 KB, swizzled

    const int tid  = threadIdx.x;
    const int w    = tid >> 6;
    const int lane = tid & 63;
    const int m16  = lane & 15;          // A-row / D-col-in-tile
    const int g    = lane >> 4;          // lane group 0..3
    const int b0   = blockIdx.x * 16;
    const int col  = w * 16 + m16;       // this lane's output column (D-layout)

    // stage z rows for this block
    for (int i = tid; i < 16 * kS; i += 1024)
        zs[i] = z[(size_t)(b0 + (i >> 9)) * kS + (i & 511)];

    const float hbj = hb[col];
    const float fbj = fb[col], ibj = ib[col], cbj = cb[col], obj = ob[col];

    // h1 master (D-layout: rows m = 4g+r, column `col`)
    float h1r[4];
    const float h0c = h0[col];
    #pragma unroll
    for (int r = 0; r < 4; ++r) h1r[r] = h0c;

    // write h1 tile (buffer 0), fp16 swizzled: byte = m*512 + n*2, ^ (m&7)<<4
    #pragma unroll
    for (int r = 0; r < 4; ++r) {
        const int m = 4 * g + r;
        const int byte = (m * 512 + col * 2) ^ ((m & 7) << 4);
        *(_Float16*)((char*)&h1A[0][0] + byte) = (_Float16)h1r[r];
    }
    __syncthreads();

    // B-fragment base (uint4 index within a matrix): (w*8 + kt)*64 + lane
    const int fbase = (w * 8) * 64 + lane;

    // per-row output offsets (element index); +t*kU each step via t*kU add
    size_t obase[4];
    #pragma unroll
    for (int r = 0; r < 4; ++r)
        obase[r] = (size_t)(b0 + 4 * g + r) * kS * kU + col;

    for (int t = 0; t < kS; ++t) {
        const int p = t & 1;

        // ---- embedding prefetch (consumed after hU mfma chain) ----
        float emb[4];
        #pragma unroll
        for (int r = 0; r < 4; ++r) {
            const int m  = 4 * g + r;
            const int zt = (t == 0) ? 0 : (zs[m * kS + t - 1] + 1);
            emb[r] = hW[zt * kU + col];
        }

        // ---- a = h1 @ hU  (8 mfma over K) ----
        f32x4 acc = {0.f, 0.f, 0.f, 0.f};
        #pragma unroll
        for (int kt = 0; kt < 8; ++kt) {
            const int abyte = (m16 * 512 + (kt * 32 + 8 * g) * 2) ^ ((m16 & 7) << 4);
            const f16x8 afr = *(const f16x8*)((const char*)&h1A[p][0] + abyte);
            const f16x8 bfr = __builtin_bit_cast(f16x8, wfrag[0 * 8192 + fbase + kt * 64]);
            acc = __builtin_amdgcn_mfma_f32_16x16x32_f16(afr, bfr, acc, 0, 0, 0);
        }

        // ---- h = tanh(a + emb + hb); write swizzled hA tile ----
        #pragma unroll
        for (int r = 0; r < 4; ++r) {
            const float hv = tanh_fast(acc[r] + emb[r] + hbj);
            const int m = 4 * g + r;
            const int byte = (m * 512 + col * 2) ^ ((m & 7) << 4);
            *(_Float16*)((char*)&hA[0] + byte) = (_Float16)hv;
        }
        __syncthreads();   // barrier 1: hA tile complete

        // ---- gates: f,i,c,o = h @ {fW,iW,cW,oW}  (32 mfma) ----
        f32x4 af = {0.f,0.f,0.f,0.f}, ai = {0.f,0.f,0.f,0.f};
        f32x4 ac = {0.f,0.f,0.f,0.f}, ao = {0.f,0.f,0.f,0.f};
        #pragma unroll 2
        for (int kt = 0; kt < 8; ++kt) {
            const int abyte = (m16 * 512 + (kt * 32 + 8 * g) * 2) ^ ((m16 & 7) << 4);
            const f16x8 afr = *(const f16x8*)((const char*)&hA[0] + abyte);
            const f16x8 bf_ = __builtin_bit_cast(f16x8, wfrag[1 * 8192 + fbase + kt * 64]);
            const f16x8 bi_ = __builtin_bit_cast(f16x8, wfrag[2 * 8192 + fbase + kt * 64]);
            const f16x8 bc_ = __builtin_bit_cast(f16x8, wfrag[3 * 8192 + fbase + kt * 64]);
            const f16x8 bo_ = __builtin_bit_cast(f16x8, wfrag[4 * 8192 + fbase + kt * 64]);
            af = __builtin_amdgcn_mfma_f32_16x16x32_f16(afr, bf_, af, 0, 0, 0);
            ai = __builtin_amdgcn_mfma_f32_16x16x32_f16(afr, bi_, ai, 0, 0, 0);
            ac = __builtin_amdgcn_mfma_f32_16x16x32_f16(afr, bc_, ac, 0, 0, 0);
            ao = __builtin_amdgcn_mfma_f32_16x16x32_f16(afr, bo_, ao, 0, 0, 0);
        }

        // ---- activations, state update, g output, next h1 tile ----
        #pragma unroll
        for (int r = 0; r < 4; ++r) {
            const float f = sigm(af[r] + fbj);
            const float i = sigm(ai[r] + ibj);
            const float c = tanh_fast(ac[r] + cbj);
            const float o = sigm(ao[r] + obj);
            h1r[r] = h1r[r] * f + c * i;
            out[obase[r] + (size_t)t * kU] = o * h1r[r];
            const int m = 4 * g + r;
            const int byte = (m * 512 + col * 2) ^ ((m & 7) << 4);
            *(_Float16*)((char*)&h1A[p ^ 1][0] + byte) = (_Float16)h1r[r];
        }
        __syncthreads();   // barrier 2: h1A[p^1] complete, hA reads done
    }
}

// ---------------------------------------------------------------------------
// Phase 2: output head (unchanged from round 2). 4096 blocks x 256 threads.
// ---------------------------------------------------------------------------
#define U4C(v, kk) ((kk) == 0 ? (v).x : (kk) == 1 ? (v).y : (kk) == 2 ? (v).z : (v).w)

__global__ __launch_bounds__(256) void rnn_phase2(
    const float* __restrict__ tb, const float* __restrict__ yb,
    const unsigned* __restrict__ wpk,
    float* __restrict__ out)
{
    __shared__ float    lg[32][kU];
    __shared__ unsigned xpk[32][kU / 2];

    const unsigned* __restrict__ tWpk = wpk;
    const unsigned* __restrict__ yWpk = wpk + kMatU32;

    const int c = threadIdx.x;
    const size_t rowbase = (size_t)blockIdx.x * 32;

    {
        const float4* src = (const float4*)&out[rowbase * kU];
        float4* dst = (float4*)&lg[0][0];
        #pragma unroll
        for (int i = 0; i < 8; ++i) dst[i * 256 + c] = src[i * 256 + c];
    }
    __syncthreads();

    #pragma unroll
    for (int i = 0; i < 16; ++i) {
        const int flat = i * 256 + c;
        const int r = flat >> 7, kp = flat & 127;
        xpk[r][kp] = packh2(lg[r][2 * kp], lg[r][2 * kp + 1]);
    }
    __syncthreads();

    float acc[32];

    {
        const float tbc = tb[c];
        #pragma unroll
        for (int r = 0; r < 32; ++r) acc[r] = tbc;
    }
    #pragma unroll 2
    for (int kp4 = 0; kp4 < 32; ++kp4) {
        const unsigned w0 = tWpk[(4 * kp4 + 0) * kU + c];
        const unsigned w1 = tWpk[(4 * kp4 + 1) * kU + c];
        const unsigned w2 = tWpk[(4 * kp4 + 2) * kU + c];
        const unsigned w3 = tWpk[(4 * kp4 + 3) * kU + c];
        #pragma unroll
        for (int r = 0; r < 32; ++r) {
            const uint4 g4 = *(const uint4*)&xpk[r][4 * kp4];
            acc[r] = dot2(w0, g4.x, acc[r]);
            acc[r] = dot2(w1, g4.y, acc[r]);
            acc[r] = dot2(w2, g4.z, acc[r]);
            acc[r] = dot2(w3, g4.w, acc[r]);
        }
    }
    __syncthreads();

    #pragma unroll
    for (int r = 0; r < 32; ++r) {
        const float th = tanh_fast(acc[r]);
        const float hh = __shfl_down(th, 1, 64);
        if ((c & 1) == 0) xpk[r][c >> 1] = packh2(th, hh);
    }
    __syncthreads();

    {
        const float ybc = yb[c];
        #pragma unroll
        for (int r = 0; r < 32; ++r) acc[r] = ybc;
    }
    #pragma unroll 2
    for (int kp4 = 0; kp4 < 32; ++kp4) {
        const unsigned w0 = yWpk[(4 * kp4 + 0) * kU + c];
        const unsigned w1 = yWpk[(4 * kp4 + 1) * kU + c];
        const unsigned w2 = yWpk[(4 * kp4 + 2) * kU + c];
        const unsigned w3 = yWpk[(4 * kp4 + 3) * kU + c];
        #pragma unroll
        for (int r = 0; r < 32; ++r) {
            const uint4 t4 = *(const uint4*)&xpk[r][4 * kp4];
            acc[r] = dot2(w0, t4.x, acc[r]);
            acc[r] = dot2(w1, t4.y, acc[r]);
            acc[r] = dot2(w2, t4.z, acc[r]);
            acc[r] = dot2(w3, t4.w, acc[r]);
        }
    }

    #pragma unroll
    for (int r = 0; r < 32; ++r) lg[r][c] = acc[r];
    __syncthreads();

    const int wv = c >> 6, lane = c & 63;
    for (int q = 0; q < 8; ++q) {
        const int r = wv * 8 + q;
        const float4 v = *(const float4*)&lg[r][lane * 4];
        float m = fmaxf(fmaxf(v.x, v.y), fmaxf(v.z, v.w));
        #pragma unroll
        for (int off = 32; off > 0; off >>= 1) m = fmaxf(m, __shfl_xor(m, off, 64));
        const float e0 = __expf(v.x - m), e1 = __expf(v.y - m);
        const float e2 = __expf(v.z - m), e3 = __expf(v.w - m);
        float s = e0 + e1 + e2 + e3;
        #pragma unroll
        for (int off = 32; off > 0; off >>= 1) s += __shfl_xor(s, off, 64);
        const float inv = 1.0f / s;
        float4 o4; o4.x = e0 * inv; o4.y = e1 * inv; o4.z = e2 * inv; o4.w = e3 * inv;
        *(float4*)&out[(rowbase + r) * kU + lane * 4] = o4;
    }
}

extern "C" void kernel_launch(void* const* d_in, const int* in_sizes, int n_in,
                              void* d_out, int out_size, void* d_ws, size_t ws_size,
                              hipStream_t stream) {
    const int*   z  = (const int*)d_in[0];
    const float* hW = (const float*)d_in[1];
    const float* hU = (const float*)d_in[2];
    const float* hb = (const float*)d_in[3];
    const float* fW = (const float*)d_in[4];
    const float* fb = (const float*)d_in[5];
    const float* iW = (const float*)d_in[6];
    const float* ib = (const float*)d_in[7];
    const float* cW = (const float*)d_in[8];
    const float* cb = (const float*)d_in[9];
    const float* oW = (const float*)d_in[10];
    const float* ob = (const float*)d_in[11];
    const float* tW = (const float*)d_in[12];
    const float* tb = (const float*)d_in[13];
    const float* yW = (const float*)d_in[14];
    const float* yb = (const float*)d_in[15];
    const float* h0 = (const float*)d_in[16];
    float* out = (float*)d_out;

    uint4*    wfrag = (uint4*)d_ws;                       // 5*8192 uint4 = 640 KB
    unsigned* wpk   = (unsigned*)d_ws + 5 * kMatU32;      // tW, yW packed pairs

    convert_frag<<<dim3(5 * 8192 / 256), dim3(256), 0, stream>>>(
        hU, fW, iW, cW, oW, wfrag);
    convert_pk<<<dim3(2 * kMatU32 / 256), dim3(256), 0, stream>>>(tW, yW, wpk);
    rnn_phase1<<<dim3(kB / 16), dim3(1024), 0, stream>>>(
        z, hW, hb, fb, ib, cb, ob, h0, wfrag, out);
    rnn_phase2<<<dim3((kB * kS) / 32), dim3(256), 0, stream>>>(
        tb, yb, wpk, out);
}